// Round 17
// baseline (178.422 us; speedup 1.0000x reference)
//
#include <hip/hip_runtime.h>
#include <hip/hip_bf16.h>
#include <stdint.h>

// out[m][n] = (sum_k x[m][k] * W[n][k]) * scale[n]
// M=8192 (B*S), N=4096 (D_OUT), K=4096 (D_IN)
// x fp32, W int32 (harness materializes integer inputs as int32), scale fp32.
// INT8 path: W exact int8; x per-row symmetric int8 (sx=amax/127).
// GEMM via mfma_i32_16x16x64_i8. Dequant: out = acc * sx[row] * scale[col].
// *** B NEVER TOUCHES LDS ***: pack_w writes W in MFMA B-fragment order
// [ktile][ngroup][lane][16B] (lane l holds W[g*16+(l&15)][t*64+(l>>4)*16+b]).
// GEMM loads B global->VGPR fully coalesced (1 KB/instr), one tile ahead,
// L2/L3-hot (16 MB). LDS carries only A: 4-buffer rotation (64 KiB), stage
// distance 3, cross-tile register prefetch, mid-body vmcnt(6)+lgkmcnt(0)+BAR,
// T19 SGB interleave. r16 bug fixed: epilogue column mapping now matches the
// pack-group layout: col = bn*256 + wc*64 + ni*16 + l15 (was ni*64 + wc*16).
// Conflict-free 64B-row swizzle on A (0 conflicts, r9-r15). T1 XCD swizzle.

#define M_TOT 8192
#define N_TOT 4096
#define K_TOT 4096
#define BM 256
#define BN 256
#define BK 64
#define NT (K_TOT / BK)   // 64 k-tiles

typedef int intx4 __attribute__((ext_vector_type(4)));

// ---- x quantization: one block per row ----
__global__ void quant_x_kernel(const float* __restrict__ x,
                               int* __restrict__ q,       // packed i8, 4/int
                               float* __restrict__ xs) {  // [M] dequant scale
  const int row = blockIdx.x;
  const int tid = threadIdx.x;
  const float4* xr = (const float4*)(x + (size_t)row * K_TOT);
  float4 v[4];
#pragma unroll
  for (int j = 0; j < 4; ++j) v[j] = xr[tid + 256 * j];
  float am = 0.f;
#pragma unroll
  for (int j = 0; j < 4; ++j) {
    am = fmaxf(am, fmaxf(fmaxf(fabsf(v[j].x), fabsf(v[j].y)),
                         fmaxf(fabsf(v[j].z), fabsf(v[j].w))));
  }
#pragma unroll
  for (int off = 32; off >= 1; off >>= 1)
    am = fmaxf(am, __shfl_xor(am, off));
  __shared__ float wmax[4];
  if ((tid & 63) == 0) wmax[tid >> 6] = am;
  __syncthreads();
  am = fmaxf(fmaxf(wmax[0], wmax[1]), fmaxf(wmax[2], wmax[3]));
  const float inv = 127.0f / fmaxf(am, 1e-30f);
  int* qo = q + (size_t)row * (K_TOT / 4);
#pragma unroll
  for (int j = 0; j < 4; ++j) {
    int b0 = __float2int_rn(v[j].x * inv);
    int b1 = __float2int_rn(v[j].y * inv);
    int b2 = __float2int_rn(v[j].z * inv);
    int b3 = __float2int_rn(v[j].w * inv);
    qo[tid + 256 * j] =
        (b0 & 255) | ((b1 & 255) << 8) | ((b2 & 255) << 16) | (b3 << 24);
  }
  if (tid == 0) xs[row] = am * (1.0f / 127.0f);
}

__device__ __forceinline__ int pack4(int4 r) {
  return (r.x & 255) | ((r.y & 255) << 8) | ((r.z & 255) << 16) | (r.w << 24);
}

// ---- W repack: int32 -> i8 in MFMA B-fragment order ----
// out[((t*256 + g)*64 + lane)*16 + b] = i8(W[g*16 + (lane&15)]
//                                           [t*64 + (lane>>4)*16 + b])
__global__ void pack_w_kernel(const int* __restrict__ in, int4* __restrict__ out) {
  const int gid = blockIdx.x * 256 + threadIdx.x;  // one 16B fragment each
  const int lane = gid & 63;
  const int g = (gid >> 6) & 255;   // n-group (16 rows)
  const int t = gid >> 14;          // k-tile
  const int row = g * 16 + (lane & 15);
  const int kb = t * 64 + (lane >> 4) * 16;
  const int4* src = (const int4*)(in + (size_t)row * K_TOT + kb);
  int4 r0 = src[0], r1 = src[1], r2 = src[2], r3 = src[3];
  int4 o;
  o.x = pack4(r0); o.y = pack4(r1); o.z = pack4(r2); o.w = pack4(r3);
  out[gid] = o;
}

// ---- async global->LDS (16B per lane, wave-uniform dest + lane*16) ----
__device__ __forceinline__ void gload_lds16(const void* g, const void* l) {
  const __attribute__((address_space(1))) void* gp =
      reinterpret_cast<const __attribute__((address_space(1))) void*>(
          reinterpret_cast<uintptr_t>(g));
  __attribute__((address_space(3))) void* lp =
      reinterpret_cast<__attribute__((address_space(3))) void*>(
          (uint32_t)reinterpret_cast<uintptr_t>(l));
  __builtin_amdgcn_global_load_lds(gp, lp, 16, 0, 0);
}

#define BAR() __builtin_amdgcn_s_barrier()
#define VMCNT(N) asm volatile("s_waitcnt vmcnt(" #N ")" ::: "memory")
#define LGKM0() asm volatile("s_waitcnt lgkmcnt(0)" ::: "memory")
#define SGB(MASK, N) __builtin_amdgcn_sched_group_barrier(MASK, N, 0)
// LLVM SchedGroupMask: MFMA=0x8, VMEM=0x10, DS_READ=0x100

// ---- main GEMM: i8, 256x256 tile, 8 waves (2x4), A-only LDS ----
__global__ __launch_bounds__(512, 2)
void wq_gemm_kernel(const char* __restrict__ A,     // [M][K] i8 (quantized x)
                    const char* __restrict__ Bp,    // fragment-packed W i8
                    const float* __restrict__ XS,   // [M] x dequant scale
                    const float* __restrict__ scale,// [N]
                    float* __restrict__ C) {        // [M][N]
  // A only: 4-buffer rotation, [buf][256 rows][64 B] = 4 x 16 KiB = 64 KiB.
  __shared__ __align__(16) char As[4][BM * BK];

  // XCD-aware block swizzle (nwg=512, divisible by 8)
  const int nb = gridDim.x;
  const int swz = (blockIdx.x & 7) * (nb >> 3) + (blockIdx.x >> 3);
  const int bm = swz >> 4;        // M/BM = 32
  const int bn = swz & 15;        // N/BN = 16

  const int tid = threadIdx.x;
  const int wave = tid >> 6, lane = tid & 63;
  const int wr = wave >> 2, wc = wave & 3;   // 2 x 4 wave grid
  const int l15 = lane & 15, lk = lane >> 4;
  const int wr16l = wr * 16 + l15;
  // Conflict-free 64B-row swizzle on A (HW-verified 0 conflicts, r9-r15):
  // phys chunk = lk ^ ((row>>1)&3); frag rows have row&15 == l15.
  const int rchunk = (lk ^ ((l15 >> 1) & 3)) << 4;  // bytes

  intx4 acc[8][4] = {};
  intx4 afL[4], afH[4], bfA[4], bfB[4];

  // A staging: one gload = 512 threads x 16B = 128 rows x 64B; 2 per tile.
  // LDS dest linear; global source chunk pre-swizzled (involution).
  const int srow = tid >> 2;                     // 0..127
  const int sc = (tid & 3) ^ ((tid >> 3) & 3);   // source 16B chunk
  const char* gA = A + (size_t)(bm * BM + srow) * K_TOT + sc * 16;
  // B fragment stream base: group g = bn*16 + wc*4 + ni; addr =
  // ((t*256 + g)*64 + lane)*16. Consecutive lanes -> consecutive 16B.
  const char* gBp = Bp + ((size_t)((bn * 16 + wc * 4) * 64 + lane) << 4);

#define STAGE_A2(P, KT)                                                   \
  do {                                                                    \
    gload_lds16(gA + (size_t)(KT) * BK, As[P] + wave * 1024);             \
    gload_lds16(gA + (size_t)128 * K_TOT + (size_t)(KT) * BK,             \
                As[P] + 8192 + wave * 1024);                              \
  } while (0)

#define DS16(BASE, ROW)                                                   \
  *(const intx4*)((BASE) + (ROW) * BK + rchunk)

#define LD_AFL(P)                                                         \
  _Pragma("unroll") for (int mi = 0; mi < 4; ++mi)                        \
      afL[mi] = DS16(As[P], mi * 32 + wr16l);
#define LD_A47(P)                                                         \
  _Pragma("unroll") for (int mi = 0; mi < 4; ++mi)                        \
      afH[mi] = DS16(As[P], (mi + 4) * 32 + wr16l);

  // B fragment loads: 4 x b128, fully coalesced (1 KB/wave/instr), L2-hot.
#define LDG_B(BF, T)                                                      \
  _Pragma("unroll") for (int ni = 0; ni < 4; ++ni)                        \
      BF[ni] = *(const intx4*)(gBp + (size_t)(T) * 262144 + ni * 1024);

  // Half-tile: 4 mi x 4 ni = 16 MFMA (K=64 each).
#define MFMA_Q(AF, BF, H)                                                 \
  _Pragma("unroll") for (int mi2 = 0; mi2 < 4; ++mi2)                     \
  _Pragma("unroll") for (int ni2 = 0; ni2 < 4; ++ni2)                     \
      acc[(H) * 4 + mi2][ni2] = __builtin_amdgcn_mfma_i32_16x16x64_i8(    \
          AF[mi2], bf ## BF[ni2], acc[(H) * 4 + mi2][ni2], 0, 0, 0);

  // SGB region 1: 16 MFMA + 4 DS_READ (A47) + 6 VMEM (4 B-loads + 2 stages).
#define SGB_R1()                                                          \
  _Pragma("unroll") for (int s1 = 0; s1 < 2; ++s1) {                      \
    SGB(0x8, 2); SGB(0x100, 1); SGB(0x8, 2); SGB(0x10, 2);                \
  }                                                                       \
  _Pragma("unroll") for (int s3 = 0; s3 < 2; ++s3) {                      \
    SGB(0x8, 2); SGB(0x100, 1); SGB(0x8, 2); SGB(0x10, 1);                \
  }
  // SGB region 2: 16 MFMA + 4 DS_READ (next-tile afL).
#define SGB_R2()                                                          \
  _Pragma("unroll") for (int s2 = 0; s2 < 4; ++s2) {                      \
    SGB(0x8, 3); SGB(0x100, 1);                                           \
  }                                                                       \
  SGB(0x8, 4);

  // body(T): region1 {MFMA0 x16 | A47 reads x4 | B(T+1)->regs x4 |
  // stage A(T+3) x2} interleaved; vmcnt(6) (B(T+1)+A(T+3) stay in flight,
  // everything older certified) + lgkmcnt(0) + BAR; region2 {afL(T+1) reads
  // x4 | MFMA1 x16} interleaved; sched_barrier(0) pins the boundary.
#define BODY(P, Q, BFC, BFN, T, STG, VMN)                                 \
  do {                                                                    \
    MFMA_Q(afL, BFC, 0);                                                  \
    LD_A47(P);                                                            \
    if ((T) + 1 < NT) { LDG_B(bf ## BFN, (T) + 1); }                      \
    if (STG) { STAGE_A2(((P) + 3) & 3, (T) + 3); }                        \
    SGB_R1();                                                             \
    VMCNT(VMN);                                                           \
    LGKM0();                                                              \
    BAR();                                                                \
    if ((T) + 1 < NT) { LD_AFL(Q); }                                      \
    MFMA_Q(afH, BFC, 1);                                                  \
    SGB_R2();                                                             \
    __builtin_amdgcn_sched_barrier(0);                                    \
  } while (0)

  // ---- prologue: B(0) first (oldest), then A(0..2); certify A(0) ----
  LDG_B(bfA, 0);
  STAGE_A2(0, 0);
  STAGE_A2(1, 1);
  STAGE_A2(2, 2);
  VMCNT(4);   // A(1),A(2) outstanding; B(0)+A(0) drained
  BAR();
  LD_AFL(0);

  // ---- main loop: 4-unrolled; bodies T..T+3 all stage A(T+3) ----
  for (int t = 0; t + 7 < NT; t += 4) {
    BODY(0, 1, A, B, t,     1, 6);
    BODY(1, 2, B, A, t + 1, 1, 6);
    BODY(2, 3, A, B, t + 2, 1, 6);
    BODY(3, 0, B, A, t + 3, 1, 6);
  }
  // tail: T=60 stages A(63); 61/62 no staging; 63 plain.
  BODY(0, 1, A, B, NT - 4, 1, 6);
  BODY(1, 2, B, A, NT - 3, 0, 6);
  BODY(2, 3, A, B, NT - 2, 0, 4);
  MFMA_Q(afL, B, 0);
  LD_A47(3);
  MFMA_Q(afH, B, 1);
#undef BODY

  // ---- epilogue: D mapping col=lane&15, row=(lane>>4)*4+e; dequant.
  // Column mapping matches the pack-group layout (r16 bugfix):
  // col = bn*256 + wc*64 + ni*16 + l15.
  const size_t crow0 = (size_t)bm * BM + wr * 16 + (lk << 2);
  const int ccol0 = bn * BN + wc * 64 + l15;
  float sc4[4];
#pragma unroll
  for (int ni = 0; ni < 4; ++ni) sc4[ni] = scale[ccol0 + ni * 16];
#pragma unroll
  for (int mi = 0; mi < 8; ++mi) {
#pragma unroll
    for (int e = 0; e < 4; ++e) {
      const size_t r = crow0 + (size_t)mi * 32 + e;
      const float xr = XS[r];
#pragma unroll
      for (int ni = 0; ni < 4; ++ni)
        C[r * N_TOT + ccol0 + ni * 16] = (float)acc[mi][ni][e] * xr * sc4[ni];
    }
  }
}

// ---- fallback if workspace too small (insurance; slow but correct) ----
__global__ void naive_kernel(const float* __restrict__ x,
                             const int* __restrict__ w,
                             const float* __restrict__ s,
                             float* __restrict__ out) {
  int m = blockIdx.y;
  int n = blockIdx.x * 256 + threadIdx.x;
  const float* xr = x + (size_t)m * K_TOT;
  const int* wr = w + (size_t)n * K_TOT;
  float acc = 0.f;
  for (int k = 0; k < K_TOT; ++k) acc += xr[k] * (float)wr[k];
  out[(size_t)m * N_TOT + n] = acc * s[n];
}

extern "C" void kernel_launch(void* const* d_in, const int* in_sizes, int n_in,
                              void* d_out, int out_size, void* d_ws, size_t ws_size,
                              hipStream_t stream) {
  const float* x = (const float*)d_in[0];
  const int* w = (const int*)d_in[1];
  const float* scale = (const float*)d_in[2];
  float* out = (float*)d_out;

  const size_t x_elems = (size_t)M_TOT * K_TOT;   // i8 bytes
  const size_t w_elems = (size_t)N_TOT * K_TOT;   // i8 bytes
  const size_t need = x_elems + w_elems + M_TOT * sizeof(float);

  if (ws_size < need) {
    dim3 g(N_TOT / 256, M_TOT);
    naive_kernel<<<g, 256, 0, stream>>>(x, w, scale, out);
    return;
  }

  char* qx = (char*)d_ws;
  char* qw = qx + x_elems;
  float* xs = (float*)(qw + w_elems);

  quant_x_kernel<<<M_TOT, 256, 0, stream>>>(x, (int*)qx, xs);
  pack_w_kernel<<<(int)(w_elems / 16 / 256), 256, 0, stream>>>(
      (const int*)w, (int4*)qw);

  wq_gemm_kernel<<<(M_TOT / BM) * (N_TOT / BN), 512, 0, stream>>>(
      qx, qw, xs, scale, out);
}